// Round 7
// baseline (4488.598 us; speedup 1.0000x reference)
//
#include <hip/hip_runtime.h>
#include <hip/hip_bf16.h>
#include <stdint.h>

typedef short short8 __attribute__((ext_vector_type(8)));
typedef float f32x4 __attribute__((ext_vector_type(4)));
typedef unsigned short u16;

__device__ __forceinline__ float bf2f(u16 b){ unsigned u = ((unsigned)b) << 16; float f; __builtin_memcpy(&f, &u, 4); return f; }
__device__ __forceinline__ u16 f2bf(float f){ unsigned u; __builtin_memcpy(&u, &f, 4); u = (u + 0x7fffu + ((u >> 16) & 1u)) >> 16; return (u16)u; }
__device__ __forceinline__ float sigm(float x){ return 1.f / (1.f + __expf(-x)); }
__device__ __forceinline__ float tanh_(float x){ float e = __expf(2.f * x); return 1.f - 2.f / (e + 1.f); }

// device-scope (coherence-point) accesses -- the ONLY scope used for h/flag exchange.
__device__ __forceinline__ short8 ld_devx4(const u16* p){
  short8 d; asm volatile("global_load_dwordx4 %0, %1, off sc0 sc1" : "=v"(d) : "v"(p) : "memory"); return d;
}
__device__ __forceinline__ int ld_dev_u32(const int* p){
  int d; asm volatile("global_load_dword %0, %1, off sc0 sc1" : "=v"(d) : "v"(p) : "memory"); return d;
}
__device__ __forceinline__ void st_dev_u16(u16* p, u16 v){
  asm volatile("global_store_short %0, %1, off sc0 sc1" :: "v"(p), "v"(v) : "memory");
}
__device__ __forceinline__ void st_dev_u32(int* p, int v){
  asm volatile("global_store_dword %0, %1, off sc0 sc1" :: "v"(p), "v"(v) : "memory");
}
__device__ __forceinline__ void wait_vm0(){ asm volatile("s_waitcnt vmcnt(0)" ::: "memory"); }
__device__ __forceinline__ void sbar0(){ __builtin_amdgcn_sched_barrier(0); }

// ---------------- init: bf16 weights, zero flags, h(-1)=state0 into slab buf 1 ----------------
// slab: [g(8)][buf(2)][slice(64)][row(8)][col(16)] bf16 ; flags: [g(8)][t(512)][slice(64)][quad(4)]
__global__ __launch_bounds__(256) void k_init(const float* __restrict__ Wih, const float* __restrict__ Whh,
                                              const float* __restrict__ s0,
                                              u16* __restrict__ Wihb, u16* __restrict__ Whhb,
                                              u16* __restrict__ slab, int* __restrict__ flags)
{
  int i = blockIdx.x * 256 + threadIdx.x;          // grid 4096*256 = 1,048,576
  int n = 3072 * 1024;
  for (int idx = i; idx < n; idx += gridDim.x * 256){
    Wihb[idx] = f2bf(Wih[idx]);
    Whhb[idx] = f2bf(Whh[idx]);
  }
  flags[i] = 0;                                     // exactly 1M flag dwords
  if (i < 65536){
    int g = i >> 13, rem = i & 8191;
    int s = rem >> 7, r = (rem >> 4) & 7, c = i & 15;
    slab[(((size_t)(g * 2 + 1) * 64 + s) * 8 + r) * 16 + c] = f2bf(s0[s * 16 + c]);
  }
}

// ---------------- xe = tanh(inputs @ W_e^T + b_e), stored bf16 [32768][1024] ----------------
__global__ __launch_bounds__(256) void k_xe(const float* __restrict__ inp, const float* __restrict__ We,
                                            const float* __restrict__ be, u16* __restrict__ xe)
{
  __shared__ float si[64][32];
  size_t m0 = (size_t)blockIdx.x * 64;
  int tid = threadIdx.x;
  for (int i = tid; i < 2048; i += 256)
    si[i >> 5][i & 31] = inp[m0 * 32 + i];
  __syncthreads();
  #pragma unroll
  for (int jj = 0; jj < 4; ++jj){
    int j = jj * 256 + tid;
    f32x4 wr[8];
    #pragma unroll
    for (int q = 0; q < 8; ++q)
      wr[q] = *(const f32x4*)(We + (size_t)j * 32 + q * 4);
    float bias = be[j];
    for (int mi = 0; mi < 64; ++mi){
      float acc = bias;
      #pragma unroll
      for (int q = 0; q < 8; ++q){
        f32x4 x = *(const f32x4*)(&si[mi][q * 4]);
        acc += x[0]*wr[q][0] + x[1]*wr[q][1] + x[2]*wr[q][2] + x[3]*wr[q][3];
      }
      xe[(m0 + mi) * 1024 + j] = f2bf(tanh_(acc));
    }
  }
}

// ---------------- xp = xe @ W_ih^T + b_ih, bf16 [32768][3072]; 128x128x32 MFMA tiles ----------------
__global__ __launch_bounds__(256) void k_xp(const u16* __restrict__ A, const u16* __restrict__ Bw,
                                            const float* __restrict__ bias, u16* __restrict__ C)
{
  __shared__ u16 As[128 * 32];
  __shared__ u16 Bs[128 * 32];
  int tid = threadIdx.x;
  int lane = tid & 63, wv = tid >> 6;
  int wr = wv >> 1, wc = wv & 1;
  int l15 = lane & 15, l4 = lane >> 4;
  int bid = blockIdx.x;
  int mb = bid / 24, nb = bid % 24;
  int m0 = mb * 128, n0 = nb * 128;

  int srow = tid >> 2;
  int sslot = tid & 3;
  int wb0 = srow * 64 + ((sslot ^ ((srow >> 1) & 3)) * 16);
  int swz = (l15 >> 1) & 3;
  int rb_ = l15 * 64 + ((l4 ^ swz) * 16);

  f32x4 acc[4][4] = {};
  const u16* Aptr = A + (size_t)m0 * 1024;
  const u16* Bptr = Bw + (size_t)n0 * 1024;

  for (int k0 = 0; k0 < 1024; k0 += 32){
    short8 va0 = *(const short8*)(Aptr + (size_t)srow * 1024 + k0 + sslot * 8);
    short8 va1 = *(const short8*)(Aptr + (size_t)(srow + 64) * 1024 + k0 + sslot * 8);
    short8 vb0 = *(const short8*)(Bptr + (size_t)srow * 1024 + k0 + sslot * 8);
    short8 vb1 = *(const short8*)(Bptr + (size_t)(srow + 64) * 1024 + k0 + sslot * 8);
    __syncthreads();
    *(short8*)((char*)As + wb0)        = va0;
    *(short8*)((char*)As + wb0 + 4096) = va1;
    *(short8*)((char*)Bs + wb0)        = vb0;
    *(short8*)((char*)Bs + wb0 + 4096) = vb1;
    __syncthreads();
    short8 af[4], bf[4];
    #pragma unroll
    for (int i = 0; i < 4; ++i){
      af[i] = *(const short8*)((const char*)As + (wr * 64 + i * 16) * 64 + rb_);
      bf[i] = *(const short8*)((const char*)Bs + (wc * 64 + i * 16) * 64 + rb_);
    }
    #pragma unroll
    for (int i = 0; i < 4; ++i)
      #pragma unroll
      for (int j = 0; j < 4; ++j)
        acc[i][j] = __builtin_amdgcn_mfma_f32_16x16x32_bf16(af[i], bf[j], acc[i][j], 0, 0, 0);
  }
  #pragma unroll
  for (int j = 0; j < 4; ++j){
    int n = n0 + wc * 64 + j * 16 + l15;
    float bv = bias[n];
    #pragma unroll
    for (int i = 0; i < 4; ++i){
      int mrow = m0 + wr * 64 + i * 16 + l4 * 4;
      #pragma unroll
      for (int r = 0; r < 4; ++r)
        C[(size_t)(mrow + r) * 3072 + n] = f2bf(acc[i][j][r] + bv);
    }
  }
}

// ---------------- GRU recurrence: two-chain pipeline, device-scope (round-3 protocol) ----------------
// 8 groups x 8 batch rows. WG (s in 0..63, p in 0..3) runs slice s (16 h-cols) for groups 2p AND
// 2p+1, sharing one set of VGPR-resident W_hh fragments. Per iteration: front(A) then front(B);
// chain A's flag latency hides under chain B's compute. Epilogue distributed: wave wv owns cols
// [wv*4, wv*4+4) (flag quad wv). One vmcnt(0) acks both chains' h stores before the flags.
__global__ __launch_bounds__(256, 1) void k_rec(const u16* __restrict__ Whhb, const float* __restrict__ bhh,
                                                const u16* __restrict__ xpb, const float* __restrict__ s0,
                                                u16* __restrict__ slab, int* __restrict__ flags,
                                                float* __restrict__ states)
{
  __shared__ f32x4 partA[4][3][64];
  __shared__ f32x4 partB[4][3][64];

  int w = blockIdx.x;
  int s = w & 63;                      // slice 0..63 (cols s*16..s*16+16)
  int p = w >> 6;                      // pair 0..3
  int gA = 2 * p, gB = 2 * p + 1;
  int tid = threadIdx.x, lane = tid & 63, wv = tid >> 6;
  int l15 = lane & 15, l4 = lane >> 4;

  // persistent W_hh fragments (shared by both chains): lane l15 = col-in-slice, wave wv owns
  // k-range [wv*256, wv*256+256)
  short8 wreg[3][8];
  #pragma unroll
  for (int gt = 0; gt < 3; ++gt){
    const u16* wp = Whhb + (size_t)(gt * 1024 + s * 16 + l15) * 1024 + wv * 256 + l4 * 8;
    #pragma unroll
    for (int ks = 0; ks < 8; ++ks)
      wreg[gt][ks] = *(const short8*)(wp + ks * 32);
  }
  float bb[3];
  #pragma unroll
  for (int gt = 0; gt < 3; ++gt) bb[gt] = bhh[gt * 1024 + s * 16 + l15];
  float hA[4], hB[4];
  { float v = s0[s * 16 + l15];
    #pragma unroll
    for (int r = 0; r < 4; ++r){ hA[r] = v; hB[r] = v; } }

  const bool ownq = ((l15 >> 2) == wv) && (l4 < 2);   // this lane stores h/states for its wave's quad
  int rowq = l4 * 4;                                   // base row for stores (l4 in {0,1})
  int xrow = (l4 & 1) * 4;                             // xq row base (dup for l4>=2)

  for (int t = 0; t < 512; ++t){
    int wb = t & 1, rb = wb ^ 1;
    // ---- xq prefetch, both chains (plain cached loads; latency hides under chain fronts) ----
    u16 xqA[12], xqB[12];
    #pragma unroll
    for (int gt = 0; gt < 3; ++gt)
      #pragma unroll
      for (int r = 0; r < 4; ++r){
        size_t col = (size_t)gt * 1024 + s * 16 + l15;
        xqA[gt * 4 + r] = xpb[((size_t)(gA * 8 + xrow + r) * 512 + t) * 3072 + col];
        xqB[gt * 4 + r] = xpb[((size_t)(gB * 8 + xrow + r) * 512 + t) * 3072 + col];
      }

    // ================= chain A front =================
    if (t > 0){
      const int* fp = flags + (((size_t)gA * 512 + (t - 1)) * 64 + wv * 16 + (lane >> 2)) * 4 + (lane & 3);
      int guard = 0;
      while (true){
        int v = ld_dev_u32(fp);
        wait_vm0(); sbar0();
        if (__all(v != 0)) break;
        __builtin_amdgcn_s_sleep(1);
        if (++guard > (1 << 18)) break;
      }
      sbar0();
    }
    short8 af[8];
    {
      const u16* base = slab + ((size_t)(gA * 2 + rb) * 64) * 128;
      #pragma unroll
      for (int ks = 0; ks < 8; ++ks){
        int slice = wv * 16 + ks * 2 + (l4 >> 1);
        af[ks] = ld_devx4(base + ((size_t)slice * 8 + (l15 & 7)) * 16 + (l4 & 1) * 8);
      }
    }
    wait_vm0(); sbar0();
    f32x4 acc[3] = {};
    #pragma unroll
    for (int ks = 0; ks < 8; ++ks)
      #pragma unroll
      for (int gt = 0; gt < 3; ++gt)
        acc[gt] = __builtin_amdgcn_mfma_f32_16x16x32_bf16(af[ks], wreg[gt][ks], acc[gt], 0, 0, 0);
    #pragma unroll
    for (int gt = 0; gt < 3; ++gt) partA[wv][gt][lane] = acc[gt];
    __syncthreads();                                  // partA visible (WAR guard: chain-B barrier)
    {
      f32x4 sr = partA[0][0][lane] + partA[1][0][lane] + partA[2][0][lane] + partA[3][0][lane];
      f32x4 sz = partA[0][1][lane] + partA[1][1][lane] + partA[2][1][lane] + partA[3][1][lane];
      f32x4 sn = partA[0][2][lane] + partA[1][2][lane] + partA[2][2][lane] + partA[3][2][lane];
      u16* hw = slab + (((size_t)(gA * 2 + wb) * 64 + s) * 8) * 16 + l15;
      #pragma unroll
      for (int r = 0; r < 4; ++r){
        float rr = sigm(bf2f(xqA[r])     + sr[r] + bb[0]);
        float zz = sigm(bf2f(xqA[4 + r]) + sz[r] + bb[1]);
        float nn = tanh_(bf2f(xqA[8 + r]) + rr * (sn[r] + bb[2]));
        float hn = (1.f - zz) * nn + zz * hA[r];
        hA[r] = hn;
        if (ownq){
          st_dev_u16(hw + (size_t)(rowq + r) * 16, f2bf(hn));
          states[((size_t)(gA * 8 + rowq + r) * 512 + t) * 1024 + s * 16 + l15] = hn;
        }
      }
    }

    // ================= chain B front =================
    if (t > 0){
      const int* fp = flags + (((size_t)gB * 512 + (t - 1)) * 64 + wv * 16 + (lane >> 2)) * 4 + (lane & 3);
      int guard = 0;
      while (true){
        int v = ld_dev_u32(fp);
        wait_vm0(); sbar0();
        if (__all(v != 0)) break;
        __builtin_amdgcn_s_sleep(1);
        if (++guard > (1 << 18)) break;
      }
      sbar0();
    }
    {
      const u16* base = slab + ((size_t)(gB * 2 + rb) * 64) * 128;
      #pragma unroll
      for (int ks = 0; ks < 8; ++ks){
        int slice = wv * 16 + ks * 2 + (l4 >> 1);
        af[ks] = ld_devx4(base + ((size_t)slice * 8 + (l15 & 7)) * 16 + (l4 & 1) * 8);
      }
    }
    wait_vm0(); sbar0();                              // also acks chain-A h stores (merged)
    f32x4 accB[3] = {};
    #pragma unroll
    for (int ks = 0; ks < 8; ++ks)
      #pragma unroll
      for (int gt = 0; gt < 3; ++gt)
        accB[gt] = __builtin_amdgcn_mfma_f32_16x16x32_bf16(af[ks], wreg[gt][ks], accB[gt], 0, 0, 0);
    #pragma unroll
    for (int gt = 0; gt < 3; ++gt) partB[wv][gt][lane] = accB[gt];
    __syncthreads();                                  // partB visible (WAR guard: chain-A barrier @t+1)
    {
      f32x4 sr = partB[0][0][lane] + partB[1][0][lane] + partB[2][0][lane] + partB[3][0][lane];
      f32x4 sz = partB[0][1][lane] + partB[1][1][lane] + partB[2][1][lane] + partB[3][1][lane];
      f32x4 sn = partB[0][2][lane] + partB[1][2][lane] + partB[2][2][lane] + partB[3][2][lane];
      u16* hw = slab + (((size_t)(gB * 2 + wb) * 64 + s) * 8) * 16 + l15;
      #pragma unroll
      for (int r = 0; r < 4; ++r){
        float rr = sigm(bf2f(xqB[r])     + sr[r] + bb[0]);
        float zz = sigm(bf2f(xqB[4 + r]) + sz[r] + bb[1]);
        float nn = tanh_(bf2f(xqB[8 + r]) + rr * (sn[r] + bb[2]));
        float hn = (1.f - zz) * nn + zz * hB[r];
        hB[r] = hn;
        if (ownq){
          st_dev_u16(hw + (size_t)(rowq + r) * 16, f2bf(hn));
          states[((size_t)(gB * 8 + rowq + r) * 512 + t) * 1024 + s * 16 + l15] = hn;
        }
      }
    }

    // ---- single ack for both chains' h stores, then both flags ----
    wait_vm0(); sbar0();
    if (lane == wv * 4){
      st_dev_u32(flags + (((size_t)gA * 512 + t) * 64 + s) * 4 + wv, 1);
      st_dev_u32(flags + (((size_t)gB * 512 + t) * 64 + s) * 4 + wv, 1);
    }
  }
}

// ---------------- outputs = states @ W_ly^T, pure fp32 ----------------
__global__ __launch_bounds__(256) void k_out(const float* __restrict__ st, const float* __restrict__ Wly,
                                             float* __restrict__ out)
{
  __shared__ float srow[8][1024];
  size_t m0 = (size_t)blockIdx.x * 8;
  int tid = threadIdx.x;
  for (int i = tid; i < 8 * 1024; i += 256)
    srow[i >> 10][i & 1023] = st[(m0 + (i >> 10)) * 1024 + (i & 1023)];
  __syncthreads();
  int mi = tid >> 5, o = tid & 31;
  const float* wp = Wly + (size_t)o * 1024;
  float acc = 0.f;
  #pragma unroll 4
  for (int k = 0; k < 1024; k += 4){
    f32x4 w = *(const f32x4*)(wp + k);
    f32x4 x = *(const f32x4*)(&srow[mi][k]);
    acc += x[0]*w[0] + x[1]*w[1] + x[2]*w[2] + x[3]*w[3];
  }
  out[(m0 + mi) * 32 + o] = acc;
}

extern "C" void kernel_launch(void* const* d_in, const int* in_sizes, int n_in,
                              void* d_out, int out_size, void* d_ws, size_t ws_size,
                              hipStream_t stream)
{
  const float* inputs = (const float*)d_in[0];
  const float* s0     = (const float*)d_in[1];
  const float* We     = (const float*)d_in[2];
  const float* be     = (const float*)d_in[3];
  const float* Wih    = (const float*)d_in[4];
  const float* bih    = (const float*)d_in[5];
  const float* Whh    = (const float*)d_in[6];
  const float* bhh    = (const float*)d_in[7];
  const float* Wly    = (const float*)d_in[8];

  float* out    = (float*)d_out;                 // (B,T,32)
  float* states = out + (size_t)64 * 512 * 32;   // (B,T,1024)

  char* ws = (char*)d_ws;
  u16* xe    = (u16*)ws;  ws += (size_t)32768 * 1024 * 2;
  u16* xpb   = (u16*)ws;  ws += (size_t)32768 * 3072 * 2;
  u16* Wihb  = (u16*)ws;  ws += (size_t)3072 * 1024 * 2;
  u16* Whhb  = (u16*)ws;  ws += (size_t)3072 * 1024 * 2;
  u16* slab  = (u16*)ws;  ws += (size_t)8 * 2 * 64 * 8 * 16 * 2;   // [g][buf][slice][8][16] bf16
  int* flags = (int*)ws;  ws += (size_t)8 * 512 * 64 * 4 * 4;      // [g][t][slice][quad]

  k_init<<<dim3(4096), dim3(256), 0, stream>>>(Wih, Whh, s0, Wihb, Whhb, slab, flags);
  k_xe<<<dim3(512), dim3(256), 0, stream>>>(inputs, We, be, xe);
  k_xp<<<dim3(6144), dim3(256), 0, stream>>>(xe, Wihb, bih, xpb);

  void* args[] = { (void*)&Whhb, (void*)&bhh, (void*)&xpb, (void*)&s0,
                   (void*)&slab, (void*)&flags, (void*)&states };
  hipError_t e = hipLaunchCooperativeKernel((const void*)k_rec, dim3(256), dim3(256), args, 0, stream);
  if (e != hipSuccess){
    (void)hipGetLastError();
    k_rec<<<dim3(256), dim3(256), 0, stream>>>(Whhb, bhh, xpb, s0, slab, flags, states);
  }
  k_out<<<dim3(4096), dim3(256), 0, stream>>>(states, Wly, out);
}

// Round 8
// 4105.902 us; speedup vs baseline: 1.0932x; 1.0932x over previous
//
#include <hip/hip_runtime.h>
#include <hip/hip_bf16.h>
#include <stdint.h>

typedef short short8 __attribute__((ext_vector_type(8)));
typedef float f32x4 __attribute__((ext_vector_type(4)));
typedef unsigned short u16;

__device__ __forceinline__ float bf2f(u16 b){ unsigned u = ((unsigned)b) << 16; float f; __builtin_memcpy(&f, &u, 4); return f; }
__device__ __forceinline__ u16 f2bf(float f){ unsigned u; __builtin_memcpy(&u, &f, 4); u = (u + 0x7fffu + ((u >> 16) & 1u)) >> 16; return (u16)u; }
__device__ __forceinline__ float sigm(float x){ return 1.f / (1.f + __expf(-x)); }
__device__ __forceinline__ float tanh_(float x){ float e = __expf(2.f * x); return 1.f - 2.f / (e + 1.f); }

// device-scope (coherence-point) accesses -- the ONLY scope used for h/flag exchange.
__device__ __forceinline__ short8 ld_devx4(const u16* p){
  short8 d; asm volatile("global_load_dwordx4 %0, %1, off sc0 sc1" : "=v"(d) : "v"(p) : "memory"); return d;
}
__device__ __forceinline__ int ld_dev_u32(const int* p){
  int d; asm volatile("global_load_dword %0, %1, off sc0 sc1" : "=v"(d) : "v"(p) : "memory"); return d;
}
__device__ __forceinline__ void st_dev_u16(u16* p, u16 v){
  asm volatile("global_store_short %0, %1, off sc0 sc1" :: "v"(p), "v"(v) : "memory");
}
__device__ __forceinline__ void st_dev_u32(int* p, int v){
  asm volatile("global_store_dword %0, %1, off sc0 sc1" :: "v"(p), "v"(v) : "memory");
}
__device__ __forceinline__ void wait_vm0(){ asm volatile("s_waitcnt vmcnt(0)" ::: "memory"); }
__device__ __forceinline__ void sbar0(){ __builtin_amdgcn_sched_barrier(0); }

// ---------------- init: bf16 weights, zero flags, h(-1)=state0 into slab buf 1 ----------------
// slab: [g(8)][buf(2)][slice(64)][row(8)][col(16)] bf16 ; flags: [g(8)][t(512)][slice(64)][quad(4)]
__global__ __launch_bounds__(256) void k_init(const float* __restrict__ Wih, const float* __restrict__ Whh,
                                              const float* __restrict__ s0,
                                              u16* __restrict__ Wihb, u16* __restrict__ Whhb,
                                              u16* __restrict__ slab, int* __restrict__ flags)
{
  int i = blockIdx.x * 256 + threadIdx.x;          // grid 4096*256 = 1,048,576
  int n = 3072 * 1024;
  for (int idx = i; idx < n; idx += gridDim.x * 256){
    Wihb[idx] = f2bf(Wih[idx]);
    Whhb[idx] = f2bf(Whh[idx]);
  }
  flags[i] = 0;                                     // exactly 1M flag dwords
  if (i < 65536){
    int g = i >> 13, rem = i & 8191;
    int s = rem >> 7, r = (rem >> 4) & 7, c = i & 15;
    slab[(((size_t)(g * 2 + 1) * 64 + s) * 8 + r) * 16 + c] = f2bf(s0[s * 16 + c]);
  }
}

// ---------------- xe = tanh(inputs @ W_e^T + b_e), stored bf16 [32768][1024] ----------------
__global__ __launch_bounds__(256) void k_xe(const float* __restrict__ inp, const float* __restrict__ We,
                                            const float* __restrict__ be, u16* __restrict__ xe)
{
  __shared__ float si[64][32];
  size_t m0 = (size_t)blockIdx.x * 64;
  int tid = threadIdx.x;
  for (int i = tid; i < 2048; i += 256)
    si[i >> 5][i & 31] = inp[m0 * 32 + i];
  __syncthreads();
  #pragma unroll
  for (int jj = 0; jj < 4; ++jj){
    int j = jj * 256 + tid;
    f32x4 wr[8];
    #pragma unroll
    for (int q = 0; q < 8; ++q)
      wr[q] = *(const f32x4*)(We + (size_t)j * 32 + q * 4);
    float bias = be[j];
    for (int mi = 0; mi < 64; ++mi){
      float acc = bias;
      #pragma unroll
      for (int q = 0; q < 8; ++q){
        f32x4 x = *(const f32x4*)(&si[mi][q * 4]);
        acc += x[0]*wr[q][0] + x[1]*wr[q][1] + x[2]*wr[q][2] + x[3]*wr[q][3];
      }
      xe[(m0 + mi) * 1024 + j] = f2bf(tanh_(acc));
    }
  }
}

// ---------------- xp = xe @ W_ih^T + b_ih, bf16 [32768][3072]; 128x128x32 MFMA tiles ----------------
__global__ __launch_bounds__(256) void k_xp(const u16* __restrict__ A, const u16* __restrict__ Bw,
                                            const float* __restrict__ bias, u16* __restrict__ C)
{
  __shared__ u16 As[128 * 32];
  __shared__ u16 Bs[128 * 32];
  int tid = threadIdx.x;
  int lane = tid & 63, wv = tid >> 6;
  int wr = wv >> 1, wc = wv & 1;
  int l15 = lane & 15, l4 = lane >> 4;
  int bid = blockIdx.x;
  int mb = bid / 24, nb = bid % 24;
  int m0 = mb * 128, n0 = nb * 128;

  int srow = tid >> 2;
  int sslot = tid & 3;
  int wb0 = srow * 64 + ((sslot ^ ((srow >> 1) & 3)) * 16);
  int swz = (l15 >> 1) & 3;
  int rb_ = l15 * 64 + ((l4 ^ swz) * 16);

  f32x4 acc[4][4] = {};
  const u16* Aptr = A + (size_t)m0 * 1024;
  const u16* Bptr = Bw + (size_t)n0 * 1024;

  for (int k0 = 0; k0 < 1024; k0 += 32){
    short8 va0 = *(const short8*)(Aptr + (size_t)srow * 1024 + k0 + sslot * 8);
    short8 va1 = *(const short8*)(Aptr + (size_t)(srow + 64) * 1024 + k0 + sslot * 8);
    short8 vb0 = *(const short8*)(Bptr + (size_t)srow * 1024 + k0 + sslot * 8);
    short8 vb1 = *(const short8*)(Bptr + (size_t)(srow + 64) * 1024 + k0 + sslot * 8);
    __syncthreads();
    *(short8*)((char*)As + wb0)        = va0;
    *(short8*)((char*)As + wb0 + 4096) = va1;
    *(short8*)((char*)Bs + wb0)        = vb0;
    *(short8*)((char*)Bs + wb0 + 4096) = vb1;
    __syncthreads();
    short8 af[4], bf[4];
    #pragma unroll
    for (int i = 0; i < 4; ++i){
      af[i] = *(const short8*)((const char*)As + (wr * 64 + i * 16) * 64 + rb_);
      bf[i] = *(const short8*)((const char*)Bs + (wc * 64 + i * 16) * 64 + rb_);
    }
    #pragma unroll
    for (int i = 0; i < 4; ++i)
      #pragma unroll
      for (int j = 0; j < 4; ++j)
        acc[i][j] = __builtin_amdgcn_mfma_f32_16x16x32_bf16(af[i], bf[j], acc[i][j], 0, 0, 0);
  }
  #pragma unroll
  for (int j = 0; j < 4; ++j){
    int n = n0 + wc * 64 + j * 16 + l15;
    float bv = bias[n];
    #pragma unroll
    for (int i = 0; i < 4; ++i){
      int mrow = m0 + wr * 64 + i * 16 + l4 * 4;
      #pragma unroll
      for (int r = 0; r < 4; ++r)
        C[(size_t)(mrow + r) * 3072 + n] = f2bf(acc[i][j][r] + bv);
    }
  }
}

// ---------------- GRU recurrence: two-chain pipeline with PER-PHASE flag stores ----------------
// 8 groups x 8 batch rows. WG (s, p) runs slice s for groups 2p and 2p+1 with shared
// VGPR-resident W_hh. Each phase: poll -> h loads -> vmcnt0 -> MFMA -> barrier -> reduce/gate
// -> h stores -> vmcnt0 -> FLAG STORE (immediately). flagA(t) propagates during phase B;
// flagB(t) during phase A of t+1 -> polls hit on first load in steady state.
__global__ __launch_bounds__(256, 1) void k_rec(const u16* __restrict__ Whhb, const float* __restrict__ bhh,
                                                const u16* __restrict__ xpb, const float* __restrict__ s0,
                                                u16* __restrict__ slab, int* __restrict__ flags,
                                                float* __restrict__ states)
{
  __shared__ f32x4 partA[4][3][64];
  __shared__ f32x4 partB[4][3][64];

  int w = blockIdx.x;
  int s = w & 63;                      // slice (cols s*16..s*16+16)
  int p = w >> 6;                      // pair 0..3
  int gA = 2 * p, gB = 2 * p + 1;
  int tid = threadIdx.x, lane = tid & 63, wv = tid >> 6;
  int l15 = lane & 15, l4 = lane >> 4;

  // persistent W_hh fragments (shared by both chains): lane l15 = col-in-slice, wave wv owns
  // k-range [wv*256, wv*256+256)
  short8 wreg[3][8];
  #pragma unroll
  for (int gt = 0; gt < 3; ++gt){
    const u16* wp = Whhb + (size_t)(gt * 1024 + s * 16 + l15) * 1024 + wv * 256 + l4 * 8;
    #pragma unroll
    for (int ks = 0; ks < 8; ++ks)
      wreg[gt][ks] = *(const short8*)(wp + ks * 32);
  }
  float bb[3];
  #pragma unroll
  for (int gt = 0; gt < 3; ++gt) bb[gt] = bhh[gt * 1024 + s * 16 + l15];
  float hA[4], hB[4];
  { float v = s0[s * 16 + l15];
    #pragma unroll
    for (int r = 0; r < 4; ++r){ hA[r] = v; hB[r] = v; } }

  const bool ownq = ((l15 >> 2) == wv) && (l4 < 2);
  int rowq = l4 * 4;
  int xrow = (l4 & 1) * 4;

  for (int t = 0; t < 512; ++t){
    int wb = t & 1, rb = wb ^ 1;

    // ---- xqA prefetch (xqB issued after phase A's flag) ----
    u16 xqA[12], xqB[12];
    #pragma unroll
    for (int gt = 0; gt < 3; ++gt)
      #pragma unroll
      for (int r = 0; r < 4; ++r)
        xqA[gt * 4 + r] = xpb[((size_t)(gA * 8 + xrow + r) * 512 + t) * 3072 + (size_t)gt * 1024 + s * 16 + l15];

    // ================= phase A =================
    if (t > 0){
      const int* fp = flags + (((size_t)gA * 512 + (t - 1)) * 64 + wv * 16 + (lane >> 2)) * 4 + (lane & 3);
      int guard = 0;
      while (true){
        int v = ld_dev_u32(fp);
        wait_vm0(); sbar0();
        if (__all(v != 0)) break;
        __builtin_amdgcn_s_sleep(1);
        if (++guard > (1 << 18)) break;
      }
      sbar0();
    }
    short8 af[8];
    {
      const u16* base = slab + ((size_t)(gA * 2 + rb) * 64) * 128;
      #pragma unroll
      for (int ks = 0; ks < 8; ++ks){
        int slice = wv * 16 + ks * 2 + (l4 >> 1);
        af[ks] = ld_devx4(base + ((size_t)slice * 8 + (l15 & 7)) * 16 + (l4 & 1) * 8);
      }
    }
    wait_vm0(); sbar0();
    f32x4 acc[3] = {};
    #pragma unroll
    for (int ks = 0; ks < 8; ++ks)
      #pragma unroll
      for (int gt = 0; gt < 3; ++gt)
        acc[gt] = __builtin_amdgcn_mfma_f32_16x16x32_bf16(af[ks], wreg[gt][ks], acc[gt], 0, 0, 0);
    #pragma unroll
    for (int gt = 0; gt < 3; ++gt) partA[wv][gt][lane] = acc[gt];
    __syncthreads();                                  // (WAR on partA guarded by sync B)
    float hnA[4];
    {
      f32x4 sr = partA[0][0][lane] + partA[1][0][lane] + partA[2][0][lane] + partA[3][0][lane];
      f32x4 sz = partA[0][1][lane] + partA[1][1][lane] + partA[2][1][lane] + partA[3][1][lane];
      f32x4 sn = partA[0][2][lane] + partA[1][2][lane] + partA[2][2][lane] + partA[3][2][lane];
      u16* hw = slab + (((size_t)(gA * 2 + wb) * 64 + s) * 8) * 16 + l15;
      #pragma unroll
      for (int r = 0; r < 4; ++r){
        float rr = sigm(bf2f(xqA[r])     + sr[r] + bb[0]);
        float zz = sigm(bf2f(xqA[4 + r]) + sz[r] + bb[1]);
        float nn = tanh_(bf2f(xqA[8 + r]) + rr * (sn[r] + bb[2]));
        hnA[r] = (1.f - zz) * nn + zz * hA[r];
        hA[r] = hnA[r];
        if (ownq) st_dev_u16(hw + (size_t)(rowq + r) * 16, f2bf(hnA[r]));
      }
    }
    wait_vm0(); sbar0();                              // h-A applied at coherence point
    if (lane == wv * 4)
      st_dev_u32(flags + (((size_t)gA * 512 + t) * 64 + s) * 4 + wv, 1);   // flagA NOW
    // deferred: states A + xqB prefetch (ack folds into phase B's vmcnt0)
    if (ownq){
      #pragma unroll
      for (int r = 0; r < 4; ++r)
        states[((size_t)(gA * 8 + rowq + r) * 512 + t) * 1024 + s * 16 + l15] = hnA[r];
    }
    #pragma unroll
    for (int gt = 0; gt < 3; ++gt)
      #pragma unroll
      for (int r = 0; r < 4; ++r)
        xqB[gt * 4 + r] = xpb[((size_t)(gB * 8 + xrow + r) * 512 + t) * 3072 + (size_t)gt * 1024 + s * 16 + l15];

    // ================= phase B =================
    if (t > 0){
      const int* fp = flags + (((size_t)gB * 512 + (t - 1)) * 64 + wv * 16 + (lane >> 2)) * 4 + (lane & 3);
      int guard = 0;
      while (true){
        int v = ld_dev_u32(fp);
        wait_vm0(); sbar0();
        if (__all(v != 0)) break;
        __builtin_amdgcn_s_sleep(1);
        if (++guard > (1 << 18)) break;
      }
      sbar0();
    }
    {
      const u16* base = slab + ((size_t)(gB * 2 + rb) * 64) * 128;
      #pragma unroll
      for (int ks = 0; ks < 8; ++ks){
        int slice = wv * 16 + ks * 2 + (l4 >> 1);
        af[ks] = ld_devx4(base + ((size_t)slice * 8 + (l15 & 7)) * 16 + (l4 & 1) * 8);
      }
    }
    wait_vm0(); sbar0();
    f32x4 accB[3] = {};
    #pragma unroll
    for (int ks = 0; ks < 8; ++ks)
      #pragma unroll
      for (int gt = 0; gt < 3; ++gt)
        accB[gt] = __builtin_amdgcn_mfma_f32_16x16x32_bf16(af[ks], wreg[gt][ks], accB[gt], 0, 0, 0);
    #pragma unroll
    for (int gt = 0; gt < 3; ++gt) partB[wv][gt][lane] = accB[gt];
    __syncthreads();                                  // (WAR on partB guarded by sync A @ t+1)
    float hnB[4];
    {
      f32x4 sr = partB[0][0][lane] + partB[1][0][lane] + partB[2][0][lane] + partB[3][0][lane];
      f32x4 sz = partB[0][1][lane] + partB[1][1][lane] + partB[2][1][lane] + partB[3][1][lane];
      f32x4 sn = partB[0][2][lane] + partB[1][2][lane] + partB[2][2][lane] + partB[3][2][lane];
      u16* hw = slab + (((size_t)(gB * 2 + wb) * 64 + s) * 8) * 16 + l15;
      #pragma unroll
      for (int r = 0; r < 4; ++r){
        float rr = sigm(bf2f(xqB[r])     + sr[r] + bb[0]);
        float zz = sigm(bf2f(xqB[4 + r]) + sz[r] + bb[1]);
        float nn = tanh_(bf2f(xqB[8 + r]) + rr * (sn[r] + bb[2]));
        hnB[r] = (1.f - zz) * nn + zz * hB[r];
        hB[r] = hnB[r];
        if (ownq) st_dev_u16(hw + (size_t)(rowq + r) * 16, f2bf(hnB[r]));
      }
    }
    wait_vm0(); sbar0();                              // h-B applied at coherence point
    if (lane == wv * 4)
      st_dev_u32(flags + (((size_t)gB * 512 + t) * 64 + s) * 4 + wv, 1);   // flagB NOW
    if (ownq){
      #pragma unroll
      for (int r = 0; r < 4; ++r)
        states[((size_t)(gB * 8 + rowq + r) * 512 + t) * 1024 + s * 16 + l15] = hnB[r];
    }
  }
}

// ---------------- outputs = states @ W_ly^T, pure fp32 ----------------
__global__ __launch_bounds__(256) void k_out(const float* __restrict__ st, const float* __restrict__ Wly,
                                             float* __restrict__ out)
{
  __shared__ float srow[8][1024];
  size_t m0 = (size_t)blockIdx.x * 8;
  int tid = threadIdx.x;
  for (int i = tid; i < 8 * 1024; i += 256)
    srow[i >> 10][i & 1023] = st[(m0 + (i >> 10)) * 1024 + (i & 1023)];
  __syncthreads();
  int mi = tid >> 5, o = tid & 31;
  const float* wp = Wly + (size_t)o * 1024;
  float acc = 0.f;
  #pragma unroll 4
  for (int k = 0; k < 1024; k += 4){
    f32x4 w = *(const f32x4*)(wp + k);
    f32x4 x = *(const f32x4*)(&srow[mi][k]);
    acc += x[0]*w[0] + x[1]*w[1] + x[2]*w[2] + x[3]*w[3];
  }
  out[(m0 + mi) * 32 + o] = acc;
}

extern "C" void kernel_launch(void* const* d_in, const int* in_sizes, int n_in,
                              void* d_out, int out_size, void* d_ws, size_t ws_size,
                              hipStream_t stream)
{
  const float* inputs = (const float*)d_in[0];
  const float* s0     = (const float*)d_in[1];
  const float* We     = (const float*)d_in[2];
  const float* be     = (const float*)d_in[3];
  const float* Wih    = (const float*)d_in[4];
  const float* bih    = (const float*)d_in[5];
  const float* Whh    = (const float*)d_in[6];
  const float* bhh    = (const float*)d_in[7];
  const float* Wly    = (const float*)d_in[8];

  float* out    = (float*)d_out;                 // (B,T,32)
  float* states = out + (size_t)64 * 512 * 32;   // (B,T,1024)

  char* ws = (char*)d_ws;
  u16* xe    = (u16*)ws;  ws += (size_t)32768 * 1024 * 2;
  u16* xpb   = (u16*)ws;  ws += (size_t)32768 * 3072 * 2;
  u16* Wihb  = (u16*)ws;  ws += (size_t)3072 * 1024 * 2;
  u16* Whhb  = (u16*)ws;  ws += (size_t)3072 * 1024 * 2;
  u16* slab  = (u16*)ws;  ws += (size_t)8 * 2 * 64 * 8 * 16 * 2;   // [g][buf][slice][8][16] bf16
  int* flags = (int*)ws;  ws += (size_t)8 * 512 * 64 * 4 * 4;      // [g][t][slice][quad]

  k_init<<<dim3(4096), dim3(256), 0, stream>>>(Wih, Whh, s0, Wihb, Whhb, slab, flags);
  k_xe<<<dim3(512), dim3(256), 0, stream>>>(inputs, We, be, xe);
  k_xp<<<dim3(6144), dim3(256), 0, stream>>>(xe, Wihb, bih, xpb);

  void* args[] = { (void*)&Whhb, (void*)&bhh, (void*)&xpb, (void*)&s0,
                   (void*)&slab, (void*)&flags, (void*)&states };
  hipError_t e = hipLaunchCooperativeKernel((const void*)k_rec, dim3(256), dim3(256), args, 0, stream);
  if (e != hipSuccess){
    (void)hipGetLastError();
    k_rec<<<dim3(256), dim3(256), 0, stream>>>(Whhb, bhh, xpb, s0, slab, flags, states);
  }
  k_out<<<dim3(4096), dim3(256), 0, stream>>>(states, Wly, out);
}